// Round 10
// baseline (414.843 us; speedup 1.0000x reference)
//
#include <hip/hip_runtime.h>

typedef unsigned short u16;
typedef __attribute__((ext_vector_type(8))) short bf16x8;   // 8 bf16 in 4 VGPRs
typedef __attribute__((ext_vector_type(4))) float f32x4;
typedef __attribute__((ext_vector_type(4))) unsigned int u32x4;

#define DIM 2048

__device__ inline u16 f2bf(float f) {
    unsigned u = __builtin_bit_cast(unsigned, f);
    u = (u + 0x7FFFu + ((u >> 16) & 1u)) >> 16;   // RNE, finite inputs only
    return (u16)u;
}

__device__ inline void gl_lds16(const void* g, void* l) {
    __builtin_amdgcn_global_load_lds(
        (const __attribute__((address_space(1))) unsigned int*)g,
        (__attribute__((address_space(3))) unsigned int*)l, 16, 0, 0);
}

struct c32 { float x, y; };
__device__ inline c32 cmul(c32 a, c32 b) { return {a.x*b.x - a.y*b.y, a.x*b.y + a.y*b.x}; }

__device__ inline int slotf(int i) { return i + (i >> 5); }   // bank-pad layout

// ---------------------------------------------------------------------------
// Kernel 1: build T = U^T, one column per block, statevector in LDS.
// (p,p+6) qubit pairing + padded layout + single buffer. Validated round 8.
// ---------------------------------------------------------------------------
__global__ __launch_bounds__(256) void build_ut(const float* __restrict__ w,
                                                u16* __restrict__ ut_re,
                                                u16* __restrict__ ut_im) {
    __shared__ alignas(16) float gre[55][4], gim[55][4];
    __shared__ alignas(16) float G4r[5][5][16], G4i[5][5][16];
    __shared__ alignas(16) u16 ptab[DIM];
    __shared__ alignas(16) float vr[DIM + (DIM >> 5)], vi[DIM + (DIM >> 5)];
    const int tid = threadIdx.x;
    const int col = blockIdx.x;

    if (tid < 55) {
        const int layer = tid / 11, q = tid - layer * 11;
        const float WM = 0.63245553203367586f;   // sqrt(2)*5^-0.5
        float hx = 0.5f * WM * w[33*layer + q];
        float hy = 0.5f * WM * w[33*layer + 11 + q];
        float hz = 0.5f * WM * w[33*layer + 22 + q];
        float cx = cosf(hx), sx = sinf(hx);
        float cy = cosf(hy), sy = sinf(hy);
        float cz = cosf(hz), sz = sinf(hz);
        c32 m00{cy*cx,  sy*sx}, m01{-sy*cx, -cy*sx};
        c32 m10{sy*cx, -cy*sx}, m11{ cy*cx, -sy*sx};
        c32 em{cz, -sz}, ep{cz, sz};
        c32 r0 = cmul(em, m00), r1 = cmul(em, m01);
        c32 r2 = cmul(ep, m10), r3 = cmul(ep, m11);
        gre[tid][0] = r0.x; gim[tid][0] = r0.y;
        gre[tid][1] = r1.x; gim[tid][1] = r1.y;
        gre[tid][2] = r2.x; gim[tid][2] = r2.y;
        gre[tid][3] = r3.x; gim[tid][3] = r3.y;
    }
    for (int i = tid; i < DIM; i += 256) {
        vr[slotf(i)] = (i == col) ? 1.0f : 0.0f;
        vi[slotf(i)] = 0.0f;
        int jj = i;
        #pragma unroll
        for (int c = 10; c >= 0; --c) {
            int sc = 10 - c;
            int st = 10 - ((c + 1) % 11);
            jj ^= ((jj >> sc) & 1) << st;
        }
        ptab[i] = (u16)slotf(jj);
    }
    __syncthreads();

    for (int t = tid; t < 400; t += 256) {
        int layer = t / 80, r = t % 80, pair = r / 16, e = r % 16;
        int v = e >> 2, vp = e & 3;
        int a = v >> 1, b = v & 1, ap = vp >> 1, bp = vp & 1;
        int gia = layer * 11 + pair;        // qubit p  (bit 10-p)
        int gib = layer * 11 + 6 + pair;    // qubit p+6 (bit 4-p)
        c32 ga{gre[gia][a*2+ap], gim[gia][a*2+ap]};
        c32 gb{gre[gib][b*2+bp], gim[gib][b*2+bp]};
        c32 pr = cmul(ga, gb);
        G4r[layer][pair][e] = pr.x; G4i[layer][pair][e] = pr.y;
    }
    __syncthreads();

    for (int layer = 0; layer < 5; ++layer) {
        for (int p = 0; p < 5; ++p) {
            const int lo = 4 - p, hi = 10 - p;
            float g4r[16], g4i[16];
            #pragma unroll
            for (int e = 0; e < 16; ++e) {
                g4r[e] = G4r[layer][p][e];
                g4i[e] = G4i[layer][p][e];
            }
            const bool permRead = (layer > 0) && (p == 0);
            if (permRead) {
                float xr[2][4], xi[2][4];
                int es[2][4];
                #pragma unroll
                for (int h = 0; h < 2; ++h) {
                    int g = tid + h * 256;
                    int tmp = ((g >> lo) << (lo + 1)) | (g & ((1 << lo) - 1));
                    int i0  = ((tmp >> hi) << (hi + 1)) | (tmp & ((1 << hi) - 1));
                    #pragma unroll
                    for (int v = 0; v < 4; ++v) {
                        int e = i0 | ((v >> 1) << hi) | ((v & 1) << lo);
                        es[h][v] = slotf(e);
                        int ss = (int)ptab[e];
                        xr[h][v] = vr[ss]; xi[h][v] = vi[ss];
                    }
                }
                __syncthreads();
                #pragma unroll
                for (int h = 0; h < 2; ++h)
                    #pragma unroll
                    for (int v = 0; v < 4; ++v) {
                        float sr = 0.f, si = 0.f;
                        #pragma unroll
                        for (int u = 0; u < 4; ++u) {
                            sr += g4r[v*4+u] * xr[h][u] - g4i[v*4+u] * xi[h][u];
                            si += g4r[v*4+u] * xi[h][u] + g4i[v*4+u] * xr[h][u];
                        }
                        vr[es[h][v]] = sr; vi[es[h][v]] = si;
                    }
                __syncthreads();
            } else {
                #pragma unroll
                for (int h = 0; h < 2; ++h) {
                    int g = tid + h * 256;
                    int tmp = ((g >> lo) << (lo + 1)) | (g & ((1 << lo) - 1));
                    int i0  = ((tmp >> hi) << (hi + 1)) | (tmp & ((1 << hi) - 1));
                    float xr[4], xi[4];
                    int es[4];
                    #pragma unroll
                    for (int v = 0; v < 4; ++v) {
                        int e = i0 | ((v >> 1) << hi) | ((v & 1) << lo);
                        es[v] = slotf(e);
                        xr[v] = vr[es[v]]; xi[v] = vi[es[v]];
                    }
                    #pragma unroll
                    for (int v = 0; v < 4; ++v) {
                        float sr = 0.f, si = 0.f;
                        #pragma unroll
                        for (int u = 0; u < 4; ++u) {
                            sr += g4r[v*4+u] * xr[u] - g4i[v*4+u] * xi[u];
                            si += g4r[v*4+u] * xi[u] + g4i[v*4+u] * xr[u];
                        }
                        vr[es[v]] = sr; vi[es[v]] = si;
                    }
                }
                __syncthreads();
            }
        }
        {
            const int gi = layer * 11 + 5;
            const float g00r = gre[gi][0], g00i = gim[gi][0];
            const float g01r = gre[gi][1], g01i = gim[gi][1];
            const float g10r = gre[gi][2], g10i = gim[gi][2];
            const float g11r = gre[gi][3], g11i = gim[gi][3];
            #pragma unroll
            for (int t = 0; t < 4; ++t) {
                int p2 = tid + t * 256;
                int i0 = ((p2 >> 5) << 6) | (p2 & 31);
                int s0 = slotf(i0), s1 = slotf(i0 + 32);
                float ar = vr[s0], ai = vi[s0];
                float br = vr[s1], bi = vi[s1];
                vr[s0] = g00r*ar - g00i*ai + g01r*br - g01i*bi;
                vi[s0] = g00r*ai + g00i*ar + g01r*bi + g01i*br;
                vr[s1] = g10r*ar - g10i*ai + g11r*br - g11i*bi;
                vi[s1] = g10r*ai + g10i*ar + g11r*bi + g11i*br;
            }
            __syncthreads();
        }
    }
    for (int i = tid; i < DIM; i += 256) {
        ut_re[(size_t)col*DIM + i] = f2bf(vr[slotf(i)]);
        ut_im[(size_t)col*DIM + i] = f2bf(vi[slotf(i)]);
    }
}

// ---------------------------------------------------------------------------
// Kernel 2: bf16 transpose (U^T -> U), 64x64 LDS tiles; z selects re/im.
// ---------------------------------------------------------------------------
__global__ __launch_bounds__(256) void transpose2(const u16* __restrict__ sre,
                                                  const u16* __restrict__ sim,
                                                  u16* __restrict__ dre,
                                                  u16* __restrict__ dim_) {
    const u16* s = blockIdx.z ? sim : sre;
    u16*       d = blockIdx.z ? dim_ : dre;
    __shared__ alignas(16) u16 tile[64][66];
    const int bx = blockIdx.x * 64, by = blockIdx.y * 64;
    for (int e = threadIdx.x; e < 1024; e += 256) {
        int r = e >> 4, c4 = (e & 15) * 4;
        uint2 v = *(const uint2*)(s + (size_t)(by + r) * DIM + bx + c4);
        u16* tp = &tile[r][c4];
        tp[0] = (u16)(v.x); tp[1] = (u16)(v.x >> 16);
        tp[2] = (u16)(v.y); tp[3] = (u16)(v.y >> 16);
    }
    __syncthreads();
    for (int e = threadIdx.x; e < 1024; e += 256) {
        int r = e >> 4, c4 = (e & 15) * 4;
        unsigned lo = (unsigned)tile[c4][r]     | ((unsigned)tile[c4+1][r] << 16);
        unsigned hi = (unsigned)tile[c4+2][r]   | ((unsigned)tile[c4+3][r] << 16);
        *(uint2*)(d + (size_t)(bx + r) * DIM + by + c4) = make_uint2(lo, hi);
    }
}

// ---------------------------------------------------------------------------
// GEMM stage 1 (MFMA, fused, LDS-FREE / barrier-free):
//   pt[m,n] = sum_k Ure[m,k] X[n,k]; qt with Uim.
// 128x128 tile, 4 waves (2x2), 4x4 16x16x32 frags. Fragments loaded straight
// from global (L2) into VGPRs: lane(ml,quad) reads 16B at row (+ml), col
// k0+quad*8 — quads form 64B-contiguous runs. No __syncthreads in the K-loop:
// the compiler software-pipelines with vmcnt(N). Register double-buffer via
// #pragma unroll 2 (compile-time buffer index, no v_mov copies).
// ---------------------------------------------------------------------------
__global__ __launch_bounds__(256) void gemm_stage1(
        const u16* __restrict__ ure, const u16* __restrict__ uim,
        const float* __restrict__ x,
        u16* __restrict__ pt, u16* __restrict__ qt) {
    const int tid  = threadIdx.x;
    const int lane = tid & 63, w = tid >> 6;
    const int m0 = blockIdx.y * 128, n0 = blockIdx.x * 128;
    const int wm = (w >> 1) * 64, wn = (w & 1) * 64;
    const int ml = lane & 15, quad = lane >> 4;

    const u16*  pAr = ure + (size_t)(m0 + wm + ml) * DIM + quad * 8;
    const u16*  pAi = uim + (size_t)(m0 + wm + ml) * DIM + quad * 8;
    const float* pB = x   + (size_t)(n0 + wn + ml) * DIM + quad * 8;

    f32x4 accP[4][4], accQ[4][4];
    #pragma unroll
    for (int i = 0; i < 4; ++i)
        #pragma unroll
        for (int j = 0; j < 4; ++j) {
            f32x4 z = {0.f, 0.f, 0.f, 0.f};
            accP[i][j] = z; accQ[i][j] = z;
        }

    bf16x8 ar[2][4], ai[2][4], bx[2][4];
    #pragma unroll
    for (int i = 0; i < 4; ++i) {
        ar[0][i] = *(const bf16x8*)(pAr + (size_t)i * 16 * DIM);
        ai[0][i] = *(const bf16x8*)(pAi + (size_t)i * 16 * DIM);
        const float4* s4 = (const float4*)(pB + (size_t)i * 16 * DIM);
        float4 v0 = s4[0], v1 = s4[1];
        u32x4 pk;
        pk.x = (unsigned)f2bf(v0.x) | ((unsigned)f2bf(v0.y) << 16);
        pk.y = (unsigned)f2bf(v0.z) | ((unsigned)f2bf(v0.w) << 16);
        pk.z = (unsigned)f2bf(v1.x) | ((unsigned)f2bf(v1.y) << 16);
        pk.w = (unsigned)f2bf(v1.z) | ((unsigned)f2bf(v1.w) << 16);
        bx[0][i] = __builtin_bit_cast(bf16x8, pk);
    }

    #pragma unroll 2
    for (int k0 = 0; k0 < DIM; k0 += 32) {
        const int cb = (k0 >> 5) & 1;
        if (k0 + 32 < DIM) {
            #pragma unroll
            for (int i = 0; i < 4; ++i) {
                ar[cb ^ 1][i] = *(const bf16x8*)(pAr + (size_t)i * 16 * DIM + k0 + 32);
                ai[cb ^ 1][i] = *(const bf16x8*)(pAi + (size_t)i * 16 * DIM + k0 + 32);
                const float4* s4 = (const float4*)(pB + (size_t)i * 16 * DIM + k0 + 32);
                float4 v0 = s4[0], v1 = s4[1];
                u32x4 pk;
                pk.x = (unsigned)f2bf(v0.x) | ((unsigned)f2bf(v0.y) << 16);
                pk.y = (unsigned)f2bf(v0.z) | ((unsigned)f2bf(v0.w) << 16);
                pk.z = (unsigned)f2bf(v1.x) | ((unsigned)f2bf(v1.y) << 16);
                pk.w = (unsigned)f2bf(v1.z) | ((unsigned)f2bf(v1.w) << 16);
                bx[cb ^ 1][i] = __builtin_bit_cast(bf16x8, pk);
            }
        }
        #pragma unroll
        for (int i = 0; i < 4; ++i)
            #pragma unroll
            for (int j = 0; j < 4; ++j) {
                accP[i][j] = __builtin_amdgcn_mfma_f32_16x16x32_bf16(ar[cb][i], bx[cb][j], accP[i][j], 0, 0, 0);
                accQ[i][j] = __builtin_amdgcn_mfma_f32_16x16x32_bf16(ai[cb][i], bx[cb][j], accQ[i][j], 0, 0, 0);
            }
    }
    // C/D layout: col = lane&15, row = quad*4 + reg
    #pragma unroll
    for (int i = 0; i < 4; ++i)
        #pragma unroll
        for (int j = 0; j < 4; ++j) {
            int row = m0 + wm + i*16 + quad*4;
            int col = n0 + wn + j*16 + ml;
            #pragma unroll
            for (int r = 0; r < 4; ++r) {
                pt[(size_t)(row + r) * DIM + col] = f2bf(accP[i][j][r]);
                qt[(size_t)(row + r) * DIM + col] = f2bf(accQ[i][j][r]);
            }
        }
}

// ---------------------------------------------------------------------------
// GEMM stage 2 (MFMA, real output, LDS-FREE / barrier-free):
//   out[m,n] = sum_j Ure[m,j] pt[n,j] + Uim[m,j] qt[n,j] = Re(U X U^H)[m,n]
// ---------------------------------------------------------------------------
__global__ __launch_bounds__(256) void gemm_stage2_real(
        const u16* __restrict__ ure, const u16* __restrict__ uim,
        const u16* __restrict__ pt, const u16* __restrict__ qt,
        float* __restrict__ out) {
    const int tid  = threadIdx.x;
    const int lane = tid & 63, w = tid >> 6;
    const int m0 = blockIdx.y * 128, n0 = blockIdx.x * 128;
    const int wm = (w >> 1) * 64, wn = (w & 1) * 64;
    const int ml = lane & 15, quad = lane >> 4;

    const u16* pAr = ure + (size_t)(m0 + wm + ml) * DIM + quad * 8;
    const u16* pAi = uim + (size_t)(m0 + wm + ml) * DIM + quad * 8;
    const u16* pBp = pt  + (size_t)(n0 + wn + ml) * DIM + quad * 8;
    const u16* pBq = qt  + (size_t)(n0 + wn + ml) * DIM + quad * 8;

    f32x4 accR[4][4];
    #pragma unroll
    for (int i = 0; i < 4; ++i)
        #pragma unroll
        for (int j = 0; j < 4; ++j) {
            f32x4 z = {0.f, 0.f, 0.f, 0.f};
            accR[i][j] = z;
        }

    bf16x8 ar[2][4], ai[2][4], bp[2][4], bq[2][4];
    #pragma unroll
    for (int i = 0; i < 4; ++i) {
        ar[0][i] = *(const bf16x8*)(pAr + (size_t)i * 16 * DIM);
        ai[0][i] = *(const bf16x8*)(pAi + (size_t)i * 16 * DIM);
        bp[0][i] = *(const bf16x8*)(pBp + (size_t)i * 16 * DIM);
        bq[0][i] = *(const bf16x8*)(pBq + (size_t)i * 16 * DIM);
    }

    #pragma unroll 2
    for (int k0 = 0; k0 < DIM; k0 += 32) {
        const int cb = (k0 >> 5) & 1;
        if (k0 + 32 < DIM) {
            #pragma unroll
            for (int i = 0; i < 4; ++i) {
                ar[cb ^ 1][i] = *(const bf16x8*)(pAr + (size_t)i * 16 * DIM + k0 + 32);
                ai[cb ^ 1][i] = *(const bf16x8*)(pAi + (size_t)i * 16 * DIM + k0 + 32);
                bp[cb ^ 1][i] = *(const bf16x8*)(pBp + (size_t)i * 16 * DIM + k0 + 32);
                bq[cb ^ 1][i] = *(const bf16x8*)(pBq + (size_t)i * 16 * DIM + k0 + 32);
            }
        }
        #pragma unroll
        for (int i = 0; i < 4; ++i)
            #pragma unroll
            for (int j = 0; j < 4; ++j) {
                accR[i][j] = __builtin_amdgcn_mfma_f32_16x16x32_bf16(ar[cb][i], bp[cb][j], accR[i][j], 0, 0, 0);
                accR[i][j] = __builtin_amdgcn_mfma_f32_16x16x32_bf16(ai[cb][i], bq[cb][j], accR[i][j], 0, 0, 0);
            }
    }
    #pragma unroll
    for (int i = 0; i < 4; ++i)
        #pragma unroll
        for (int j = 0; j < 4; ++j) {
            int row = m0 + wm + i*16 + quad*4;
            int col = n0 + wn + j*16 + ml;
            #pragma unroll
            for (int r = 0; r < 4; ++r)
                out[(size_t)(row + r) * DIM + col] = accR[i][j][r];
        }
}

// ---------------------------------------------------------------------------
// Fallback (complex interleaved output) — insurance only, 128x128 1-buf LDS.
// ---------------------------------------------------------------------------
__global__ __launch_bounds__(256, 1) void gemm_stage2_cplx(
        const u16* __restrict__ ure, const u16* __restrict__ uim,
        const u16* __restrict__ pt, const u16* __restrict__ qt,
        float2* __restrict__ out, size_t out_lim) {
    __shared__ alignas(16) u16 Ar[128*32], Ai[128*32], Bp[128*32], Bq[128*32];
    const int tid  = threadIdx.x;
    const int lane = tid & 63, w = tid >> 6;
    const int m0 = blockIdx.y * 128, n0 = blockIdx.x * 128;
    const int wm = (w >> 1) * 64, wn = (w & 1) * 64;
    const int ml = lane & 15, quad = lane >> 4;

    f32x4 accR[4][4], accI[4][4];
    #pragma unroll
    for (int i = 0; i < 4; ++i)
        #pragma unroll
        for (int j = 0; j < 4; ++j) {
            f32x4 z = {0.f, 0.f, 0.f, 0.f};
            accR[i][j] = z; accI[i][j] = z;
        }

    for (int k0 = 0; k0 < DIM; k0 += 32) {
        #pragma unroll
        for (int t = 0; t < 2; ++t) {
            int ci = t * 256 + tid;
            int r = ci >> 2, c = ci & 3;
            size_t goA = ((size_t)(m0 + r) * DIM + k0) * 2 + c * 16;
            size_t goB = ((size_t)(n0 + r) * DIM + k0) * 2 + c * 16;
            gl_lds16((const char*)ure + goA, (char*)Ar + ci * 16);
            gl_lds16((const char*)uim + goA, (char*)Ai + ci * 16);
            gl_lds16((const char*)pt  + goB, (char*)Bp + ci * 16);
            gl_lds16((const char*)qt  + goB, (char*)Bq + ci * 16);
        }
        __syncthreads();
        bf16x8 ar[4], ai[4], bp[4], bq[4];
        #pragma unroll
        for (int i = 0; i < 4; ++i) {
            ar[i] = *(const bf16x8*)(Ar + (wm + i*16 + ml) * 32 + quad * 8);
            ai[i] = *(const bf16x8*)(Ai + (wm + i*16 + ml) * 32 + quad * 8);
            bp[i] = *(const bf16x8*)(Bp + (wn + i*16 + ml) * 32 + quad * 8);
            bq[i] = *(const bf16x8*)(Bq + (wn + i*16 + ml) * 32 + quad * 8);
        }
        #pragma unroll
        for (int i = 0; i < 4; ++i)
            #pragma unroll
            for (int j = 0; j < 4; ++j) {
                accR[i][j] = __builtin_amdgcn_mfma_f32_16x16x32_bf16(ar[i], bp[j], accR[i][j], 0, 0, 0);
                accR[i][j] = __builtin_amdgcn_mfma_f32_16x16x32_bf16(ai[i], bq[j], accR[i][j], 0, 0, 0);
                accI[i][j] = __builtin_amdgcn_mfma_f32_16x16x32_bf16(ai[i], bp[j], accI[i][j], 0, 0, 0);
                f32x4 t2 = __builtin_amdgcn_mfma_f32_16x16x32_bf16(ar[i], bq[j], {0.f,0.f,0.f,0.f}, 0, 0, 0);
                accI[i][j] -= t2;
            }
        __syncthreads();
    }
    #pragma unroll
    for (int i = 0; i < 4; ++i)
        #pragma unroll
        for (int j = 0; j < 4; ++j) {
            int row = m0 + wm + i*16 + quad*4;
            int col = n0 + wn + j*16 + ml;
            #pragma unroll
            for (int r = 0; r < 4; ++r) {
                size_t idx = (size_t)(row + r) * DIM + col;
                if (idx < out_lim)
                    out[idx] = make_float2(accR[i][j][r], accI[i][j][r]);
            }
        }
}

// ---------------------------------------------------------------------------
extern "C" void kernel_launch(void* const* d_in, const int* in_sizes, int n_in,
                              void* d_out, int out_size, void* d_ws, size_t ws_size,
                              hipStream_t stream) {
    int xi = (in_sizes[0] >= in_sizes[1]) ? 0 : 1;
    const float* x = (const float*)d_in[xi];
    const float* w = (const float*)d_in[1 - xi];

    char* ws = (char*)d_ws;
    const size_t P = (size_t)DIM * DIM * 2;   // one bf16 plane = 8 MiB
    if (ws_size < 4 * P) return;

    u16* ut_re = (u16*)(ws);
    u16* ut_im = (u16*)(ws + P);
    u16* u_re  = (u16*)(ws + 2*P);
    u16* u_im  = (u16*)(ws + 3*P);
    u16* pt    = ut_re;   // reuse after transpose
    u16* qt    = ut_im;

    build_ut<<<DIM, 256, 0, stream>>>(w, ut_re, ut_im);
    transpose2<<<dim3(32, 32, 2), 256, 0, stream>>>(ut_re, ut_im, u_re, u_im);
    gemm_stage1<<<dim3(16, 16), 256, 0, stream>>>(u_re, u_im, x, pt, qt);

    if (out_size == DIM * DIM) {
        gemm_stage2_real<<<dim3(16, 16), 256, 0, stream>>>(u_re, u_im, pt, qt,
                                                           (float*)d_out);
    } else {
        gemm_stage2_cplx<<<dim3(16, 16), 256, 0, stream>>>(u_re, u_im, pt, qt,
                                                           (float2*)d_out,
                                                           (size_t)out_size / 2);
    }
}

// Round 11
// 308.189 us; speedup vs baseline: 1.3461x; 1.3461x over previous
//
#include <hip/hip_runtime.h>

typedef unsigned short u16;
typedef __attribute__((ext_vector_type(8))) short bf16x8;   // 8 bf16 in 4 VGPRs
typedef __attribute__((ext_vector_type(4))) float f32x4;
typedef __attribute__((ext_vector_type(4))) unsigned int u32x4;

#define DIM 2048

__device__ inline u16 f2bf(float f) {
    unsigned u = __builtin_bit_cast(unsigned, f);
    u = (u + 0x7FFFu + ((u >> 16) & 1u)) >> 16;   // RNE, finite inputs only
    return (u16)u;
}

__device__ inline void gl_lds16(const void* g, void* l) {
    __builtin_amdgcn_global_load_lds(
        (const __attribute__((address_space(1))) unsigned int*)g,
        (__attribute__((address_space(3))) unsigned int*)l, 16, 0, 0);
}

struct c32 { float x, y; };
__device__ inline c32 cmul(c32 a, c32 b) { return {a.x*b.x - a.y*b.y, a.x*b.y + a.y*b.x}; }

__device__ inline int slotf(int i) { return i + (i >> 5); }   // bank-pad layout

// ---------------------------------------------------------------------------
// Kernel 1: build T = U^T, one column per block, statevector in LDS.
// (p,p+6) qubit pairing + padded layout + single buffer. Validated round 8.
// ---------------------------------------------------------------------------
__global__ __launch_bounds__(256) void build_ut(const float* __restrict__ w,
                                                u16* __restrict__ ut_re,
                                                u16* __restrict__ ut_im) {
    __shared__ alignas(16) float gre[55][4], gim[55][4];
    __shared__ alignas(16) float G4r[5][5][16], G4i[5][5][16];
    __shared__ alignas(16) u16 ptab[DIM];
    __shared__ alignas(16) float vr[DIM + (DIM >> 5)], vi[DIM + (DIM >> 5)];
    const int tid = threadIdx.x;
    const int col = blockIdx.x;

    if (tid < 55) {
        const int layer = tid / 11, q = tid - layer * 11;
        const float WM = 0.63245553203367586f;   // sqrt(2)*5^-0.5
        float hx = 0.5f * WM * w[33*layer + q];
        float hy = 0.5f * WM * w[33*layer + 11 + q];
        float hz = 0.5f * WM * w[33*layer + 22 + q];
        float cx = cosf(hx), sx = sinf(hx);
        float cy = cosf(hy), sy = sinf(hy);
        float cz = cosf(hz), sz = sinf(hz);
        c32 m00{cy*cx,  sy*sx}, m01{-sy*cx, -cy*sx};
        c32 m10{sy*cx, -cy*sx}, m11{ cy*cx, -sy*sx};
        c32 em{cz, -sz}, ep{cz, sz};
        c32 r0 = cmul(em, m00), r1 = cmul(em, m01);
        c32 r2 = cmul(ep, m10), r3 = cmul(ep, m11);
        gre[tid][0] = r0.x; gim[tid][0] = r0.y;
        gre[tid][1] = r1.x; gim[tid][1] = r1.y;
        gre[tid][2] = r2.x; gim[tid][2] = r2.y;
        gre[tid][3] = r3.x; gim[tid][3] = r3.y;
    }
    for (int i = tid; i < DIM; i += 256) {
        vr[slotf(i)] = (i == col) ? 1.0f : 0.0f;
        vi[slotf(i)] = 0.0f;
        int jj = i;
        #pragma unroll
        for (int c = 10; c >= 0; --c) {
            int sc = 10 - c;
            int st = 10 - ((c + 1) % 11);
            jj ^= ((jj >> sc) & 1) << st;
        }
        ptab[i] = (u16)slotf(jj);
    }
    __syncthreads();

    for (int t = tid; t < 400; t += 256) {
        int layer = t / 80, r = t % 80, pair = r / 16, e = r % 16;
        int v = e >> 2, vp = e & 3;
        int a = v >> 1, b = v & 1, ap = vp >> 1, bp = vp & 1;
        int gia = layer * 11 + pair;        // qubit p  (bit 10-p)
        int gib = layer * 11 + 6 + pair;    // qubit p+6 (bit 4-p)
        c32 ga{gre[gia][a*2+ap], gim[gia][a*2+ap]};
        c32 gb{gre[gib][b*2+bp], gim[gib][b*2+bp]};
        c32 pr = cmul(ga, gb);
        G4r[layer][pair][e] = pr.x; G4i[layer][pair][e] = pr.y;
    }
    __syncthreads();

    for (int layer = 0; layer < 5; ++layer) {
        for (int p = 0; p < 5; ++p) {
            const int lo = 4 - p, hi = 10 - p;
            float g4r[16], g4i[16];
            #pragma unroll
            for (int e = 0; e < 16; ++e) {
                g4r[e] = G4r[layer][p][e];
                g4i[e] = G4i[layer][p][e];
            }
            const bool permRead = (layer > 0) && (p == 0);
            if (permRead) {
                float xr[2][4], xi[2][4];
                int es[2][4];
                #pragma unroll
                for (int h = 0; h < 2; ++h) {
                    int g = tid + h * 256;
                    int tmp = ((g >> lo) << (lo + 1)) | (g & ((1 << lo) - 1));
                    int i0  = ((tmp >> hi) << (hi + 1)) | (tmp & ((1 << hi) - 1));
                    #pragma unroll
                    for (int v = 0; v < 4; ++v) {
                        int e = i0 | ((v >> 1) << hi) | ((v & 1) << lo);
                        es[h][v] = slotf(e);
                        int ss = (int)ptab[e];
                        xr[h][v] = vr[ss]; xi[h][v] = vi[ss];
                    }
                }
                __syncthreads();
                #pragma unroll
                for (int h = 0; h < 2; ++h)
                    #pragma unroll
                    for (int v = 0; v < 4; ++v) {
                        float sr = 0.f, si = 0.f;
                        #pragma unroll
                        for (int u = 0; u < 4; ++u) {
                            sr += g4r[v*4+u] * xr[h][u] - g4i[v*4+u] * xi[h][u];
                            si += g4r[v*4+u] * xi[h][u] + g4i[v*4+u] * xr[h][u];
                        }
                        vr[es[h][v]] = sr; vi[es[h][v]] = si;
                    }
                __syncthreads();
            } else {
                #pragma unroll
                for (int h = 0; h < 2; ++h) {
                    int g = tid + h * 256;
                    int tmp = ((g >> lo) << (lo + 1)) | (g & ((1 << lo) - 1));
                    int i0  = ((tmp >> hi) << (hi + 1)) | (tmp & ((1 << hi) - 1));
                    float xr[4], xi[4];
                    int es[4];
                    #pragma unroll
                    for (int v = 0; v < 4; ++v) {
                        int e = i0 | ((v >> 1) << hi) | ((v & 1) << lo);
                        es[v] = slotf(e);
                        xr[v] = vr[es[v]]; xi[v] = vi[es[v]];
                    }
                    #pragma unroll
                    for (int v = 0; v < 4; ++v) {
                        float sr = 0.f, si = 0.f;
                        #pragma unroll
                        for (int u = 0; u < 4; ++u) {
                            sr += g4r[v*4+u] * xr[u] - g4i[v*4+u] * xi[u];
                            si += g4r[v*4+u] * xi[u] + g4i[v*4+u] * xr[u];
                        }
                        vr[es[v]] = sr; vi[es[v]] = si;
                    }
                }
                __syncthreads();
            }
        }
        {
            const int gi = layer * 11 + 5;
            const float g00r = gre[gi][0], g00i = gim[gi][0];
            const float g01r = gre[gi][1], g01i = gim[gi][1];
            const float g10r = gre[gi][2], g10i = gim[gi][2];
            const float g11r = gre[gi][3], g11i = gim[gi][3];
            #pragma unroll
            for (int t = 0; t < 4; ++t) {
                int p2 = tid + t * 256;
                int i0 = ((p2 >> 5) << 6) | (p2 & 31);
                int s0 = slotf(i0), s1 = slotf(i0 + 32);
                float ar = vr[s0], ai = vi[s0];
                float br = vr[s1], bi = vi[s1];
                vr[s0] = g00r*ar - g00i*ai + g01r*br - g01i*bi;
                vi[s0] = g00r*ai + g00i*ar + g01r*bi + g01i*br;
                vr[s1] = g10r*ar - g10i*ai + g11r*br - g11i*bi;
                vi[s1] = g10r*ai + g10i*ar + g11r*bi + g11i*br;
            }
            __syncthreads();
        }
    }
    for (int i = tid; i < DIM; i += 256) {
        ut_re[(size_t)col*DIM + i] = f2bf(vr[slotf(i)]);
        ut_im[(size_t)col*DIM + i] = f2bf(vi[slotf(i)]);
    }
}

// ---------------------------------------------------------------------------
// Kernel 2: bf16 transpose (U^T -> U), 64x64 LDS tiles; z selects re/im.
// ---------------------------------------------------------------------------
__global__ __launch_bounds__(256) void transpose2(const u16* __restrict__ sre,
                                                  const u16* __restrict__ sim,
                                                  u16* __restrict__ dre,
                                                  u16* __restrict__ dim_) {
    const u16* s = blockIdx.z ? sim : sre;
    u16*       d = blockIdx.z ? dim_ : dre;
    __shared__ alignas(16) u16 tile[64][66];
    const int bx = blockIdx.x * 64, by = blockIdx.y * 64;
    for (int e = threadIdx.x; e < 1024; e += 256) {
        int r = e >> 4, c4 = (e & 15) * 4;
        uint2 v = *(const uint2*)(s + (size_t)(by + r) * DIM + bx + c4);
        u16* tp = &tile[r][c4];
        tp[0] = (u16)(v.x); tp[1] = (u16)(v.x >> 16);
        tp[2] = (u16)(v.y); tp[3] = (u16)(v.y >> 16);
    }
    __syncthreads();
    for (int e = threadIdx.x; e < 1024; e += 256) {
        int r = e >> 4, c4 = (e & 15) * 4;
        unsigned lo = (unsigned)tile[c4][r]     | ((unsigned)tile[c4+1][r] << 16);
        unsigned hi = (unsigned)tile[c4+2][r]   | ((unsigned)tile[c4+3][r] << 16);
        *(uint2*)(d + (size_t)(bx + r) * DIM + by + c4) = make_uint2(lo, hi);
    }
}

// ---------------------------------------------------------------------------
// GEMM stage 1 (MFMA, PRODUCT-SPLIT, 128x128, LDS double-buffered):
//   z=0: pt[m,n] = sum_k Ure[m,k] X[n,k];  z=1: qt with Uim.
// Grid (16,16,2) = 512 blocks = 2 blocks/CU: co-resident blocks hide each
// other's barrier drain (m114) at UNCHANGED per-block intensity.
// LDS 2 bufs x 2 planes x 8KB = 32KB.
// ---------------------------------------------------------------------------
__global__ __launch_bounds__(256, 2) void gemm_stage1(
        const u16* __restrict__ ure, const u16* __restrict__ uim,
        const float* __restrict__ x,
        u16* __restrict__ pt, u16* __restrict__ qt) {
    __shared__ alignas(16) u16 Ab[2][128*32], Bx[2][128*32];
    const u16* A  = blockIdx.z ? uim : ure;
    u16*      dst = blockIdx.z ? qt  : pt;
    const int tid  = threadIdx.x;
    const int lane = tid & 63, w = tid >> 6;
    const int m0 = blockIdx.y * 128, n0 = blockIdx.x * 128;
    const int wm = (w >> 1) * 64, wn = (w & 1) * 64;
    const int ml = lane & 15, quad = lane >> 4;

    f32x4 acc[4][4];
    #pragma unroll
    for (int i = 0; i < 4; ++i)
        #pragma unroll
        for (int j = 0; j < 4; ++j) {
            f32x4 z = {0.f, 0.f, 0.f, 0.f};
            acc[i][j] = z;
        }

    auto stage = [&](int b, int k0) {
        #pragma unroll
        for (int t = 0; t < 2; ++t) {
            int ci = t * 256 + tid;          // 16B chunk = 8 bf16
            int r = ci >> 2, c = ci & 3;
            size_t goA = ((size_t)(m0 + r) * DIM + k0) * 2 + c * 16;
            gl_lds16((const char*)A + goA, (char*)Ab[b] + ci * 16);
            const float4* src = (const float4*)(x + (size_t)(n0 + r) * DIM + k0 + c * 8);
            float4 v0 = src[0], v1 = src[1];
            u32x4 pk;
            pk.x = (unsigned)f2bf(v0.x) | ((unsigned)f2bf(v0.y) << 16);
            pk.y = (unsigned)f2bf(v0.z) | ((unsigned)f2bf(v0.w) << 16);
            pk.z = (unsigned)f2bf(v1.x) | ((unsigned)f2bf(v1.y) << 16);
            pk.w = (unsigned)f2bf(v1.z) | ((unsigned)f2bf(v1.w) << 16);
            *(u32x4*)((char*)Bx[b] + ci * 16) = pk;
        }
    };

    stage(0, 0);
    __syncthreads();

    for (int k0 = 0; k0 < DIM; k0 += 32) {
        const int cb = (k0 >> 5) & 1;
        if (k0 + 32 < DIM) stage(cb ^ 1, k0 + 32);   // prefetch next tile

        bf16x8 af[4], bf[4];
        #pragma unroll
        for (int i = 0; i < 4; ++i) {
            af[i] = *(const bf16x8*)(Ab[cb] + (wm + i*16 + ml) * 32 + quad * 8);
            bf[i] = *(const bf16x8*)(Bx[cb] + (wn + i*16 + ml) * 32 + quad * 8);
        }
        #pragma unroll
        for (int i = 0; i < 4; ++i)
            #pragma unroll
            for (int j = 0; j < 4; ++j)
                acc[i][j] = __builtin_amdgcn_mfma_f32_16x16x32_bf16(af[i], bf[j], acc[i][j], 0, 0, 0);
        __syncthreads();
    }
    // C/D layout: col = lane&15, row = quad*4 + reg
    #pragma unroll
    for (int i = 0; i < 4; ++i)
        #pragma unroll
        for (int j = 0; j < 4; ++j) {
            int row = m0 + wm + i*16 + quad*4;
            int col = n0 + wn + j*16 + ml;
            #pragma unroll
            for (int r = 0; r < 4; ++r)
                dst[(size_t)(row + r) * DIM + col] = f2bf(acc[i][j][r]);
        }
}

// ---------------------------------------------------------------------------
// GEMM stage 2 (MFMA, PRODUCT-SPLIT, real output via fp32 atomics):
//   z=0 adds Ure@pt^T tile, z=1 adds Uim@qt^T tile into memset d_out.
//   out[m,n] = Ure X Ure^T + Uim X Uim^T = Re(U X U^H).
// unsafeAtomicAdd -> hardware global_atomic_add_f32 (no CAS loop).
// ---------------------------------------------------------------------------
__global__ __launch_bounds__(256, 2) void gemm_stage2_atomic(
        const u16* __restrict__ ure, const u16* __restrict__ uim,
        const u16* __restrict__ pt, const u16* __restrict__ qt,
        float* __restrict__ out) {
    __shared__ alignas(16) u16 Ab[2][128*32], Bb[2][128*32];
    const u16* A = blockIdx.z ? uim : ure;
    const u16* B = blockIdx.z ? qt  : pt;
    const int tid  = threadIdx.x;
    const int lane = tid & 63, w = tid >> 6;
    const int m0 = blockIdx.y * 128, n0 = blockIdx.x * 128;
    const int wm = (w >> 1) * 64, wn = (w & 1) * 64;
    const int ml = lane & 15, quad = lane >> 4;

    f32x4 acc[4][4];
    #pragma unroll
    for (int i = 0; i < 4; ++i)
        #pragma unroll
        for (int j = 0; j < 4; ++j) {
            f32x4 z = {0.f, 0.f, 0.f, 0.f};
            acc[i][j] = z;
        }

    auto stage = [&](int b, int k0) {
        #pragma unroll
        for (int t = 0; t < 2; ++t) {
            int ci = t * 256 + tid;
            int r = ci >> 2, c = ci & 3;
            size_t goA = ((size_t)(m0 + r) * DIM + k0) * 2 + c * 16;
            size_t goB = ((size_t)(n0 + r) * DIM + k0) * 2 + c * 16;
            gl_lds16((const char*)A + goA, (char*)Ab[b] + ci * 16);
            gl_lds16((const char*)B + goB, (char*)Bb[b] + ci * 16);
        }
    };

    stage(0, 0);
    __syncthreads();

    for (int k0 = 0; k0 < DIM; k0 += 32) {
        const int cb = (k0 >> 5) & 1;
        if (k0 + 32 < DIM) stage(cb ^ 1, k0 + 32);   // prefetch next tile

        bf16x8 af[4], bf[4];
        #pragma unroll
        for (int i = 0; i < 4; ++i) {
            af[i] = *(const bf16x8*)(Ab[cb] + (wm + i*16 + ml) * 32 + quad * 8);
            bf[i] = *(const bf16x8*)(Bb[cb] + (wn + i*16 + ml) * 32 + quad * 8);
        }
        #pragma unroll
        for (int i = 0; i < 4; ++i)
            #pragma unroll
            for (int j = 0; j < 4; ++j)
                acc[i][j] = __builtin_amdgcn_mfma_f32_16x16x32_bf16(af[i], bf[j], acc[i][j], 0, 0, 0);
        __syncthreads();
    }
    #pragma unroll
    for (int i = 0; i < 4; ++i)
        #pragma unroll
        for (int j = 0; j < 4; ++j) {
            int row = m0 + wm + i*16 + quad*4;
            int col = n0 + wn + j*16 + ml;
            #pragma unroll
            for (int r = 0; r < 4; ++r)
                unsafeAtomicAdd(&out[(size_t)(row + r) * DIM + col], acc[i][j][r]);
        }
}

// ---------------------------------------------------------------------------
// Fallback (complex interleaved output) — insurance only, 128x128 1-buf LDS.
// ---------------------------------------------------------------------------
__global__ __launch_bounds__(256, 1) void gemm_stage2_cplx(
        const u16* __restrict__ ure, const u16* __restrict__ uim,
        const u16* __restrict__ pt, const u16* __restrict__ qt,
        float2* __restrict__ out, size_t out_lim) {
    __shared__ alignas(16) u16 Ar[128*32], Ai[128*32], Bp[128*32], Bq[128*32];
    const int tid  = threadIdx.x;
    const int lane = tid & 63, w = tid >> 6;
    const int m0 = blockIdx.y * 128, n0 = blockIdx.x * 128;
    const int wm = (w >> 1) * 64, wn = (w & 1) * 64;
    const int ml = lane & 15, quad = lane >> 4;

    f32x4 accR[4][4], accI[4][4];
    #pragma unroll
    for (int i = 0; i < 4; ++i)
        #pragma unroll
        for (int j = 0; j < 4; ++j) {
            f32x4 z = {0.f, 0.f, 0.f, 0.f};
            accR[i][j] = z; accI[i][j] = z;
        }

    for (int k0 = 0; k0 < DIM; k0 += 32) {
        #pragma unroll
        for (int t = 0; t < 2; ++t) {
            int ci = t * 256 + tid;
            int r = ci >> 2, c = ci & 3;
            size_t goA = ((size_t)(m0 + r) * DIM + k0) * 2 + c * 16;
            size_t goB = ((size_t)(n0 + r) * DIM + k0) * 2 + c * 16;
            gl_lds16((const char*)ure + goA, (char*)Ar + ci * 16);
            gl_lds16((const char*)uim + goA, (char*)Ai + ci * 16);
            gl_lds16((const char*)pt  + goB, (char*)Bp + ci * 16);
            gl_lds16((const char*)qt  + goB, (char*)Bq + ci * 16);
        }
        __syncthreads();
        bf16x8 ar[4], ai[4], bp[4], bq[4];
        #pragma unroll
        for (int i = 0; i < 4; ++i) {
            ar[i] = *(const bf16x8*)(Ar + (wm + i*16 + ml) * 32 + quad * 8);
            ai[i] = *(const bf16x8*)(Ai + (wm + i*16 + ml) * 32 + quad * 8);
            bp[i] = *(const bf16x8*)(Bp + (wn + i*16 + ml) * 32 + quad * 8);
            bq[i] = *(const bf16x8*)(Bq + (wn + i*16 + ml) * 32 + quad * 8);
        }
        #pragma unroll
        for (int i = 0; i < 4; ++i)
            #pragma unroll
            for (int j = 0; j < 4; ++j) {
                accR[i][j] = __builtin_amdgcn_mfma_f32_16x16x32_bf16(ar[i], bp[j], accR[i][j], 0, 0, 0);
                accR[i][j] = __builtin_amdgcn_mfma_f32_16x16x32_bf16(ai[i], bq[j], accR[i][j], 0, 0, 0);
                accI[i][j] = __builtin_amdgcn_mfma_f32_16x16x32_bf16(ai[i], bp[j], accI[i][j], 0, 0, 0);
                f32x4 t2 = __builtin_amdgcn_mfma_f32_16x16x32_bf16(ar[i], bq[j], {0.f,0.f,0.f,0.f}, 0, 0, 0);
                accI[i][j] -= t2;
            }
        __syncthreads();
    }
    #pragma unroll
    for (int i = 0; i < 4; ++i)
        #pragma unroll
        for (int j = 0; j < 4; ++j) {
            int row = m0 + wm + i*16 + quad*4;
            int col = n0 + wn + j*16 + ml;
            #pragma unroll
            for (int r = 0; r < 4; ++r) {
                size_t idx = (size_t)(row + r) * DIM + col;
                if (idx < out_lim)
                    out[idx] = make_float2(accR[i][j][r], accI[i][j][r]);
            }
        }
}

// ---------------------------------------------------------------------------
extern "C" void kernel_launch(void* const* d_in, const int* in_sizes, int n_in,
                              void* d_out, int out_size, void* d_ws, size_t ws_size,
                              hipStream_t stream) {
    int xi = (in_sizes[0] >= in_sizes[1]) ? 0 : 1;
    const float* x = (const float*)d_in[xi];
    const float* w = (const float*)d_in[1 - xi];

    char* ws = (char*)d_ws;
    const size_t P = (size_t)DIM * DIM * 2;   // one bf16 plane = 8 MiB
    if (ws_size < 4 * P) return;

    u16* ut_re = (u16*)(ws);
    u16* ut_im = (u16*)(ws + P);
    u16* u_re  = (u16*)(ws + 2*P);
    u16* u_im  = (u16*)(ws + 3*P);
    u16* pt    = ut_re;   // reuse after transpose
    u16* qt    = ut_im;

    build_ut<<<DIM, 256, 0, stream>>>(w, ut_re, ut_im);
    transpose2<<<dim3(32, 32, 2), 256, 0, stream>>>(ut_re, ut_im, u_re, u_im);
    gemm_stage1<<<dim3(16, 16, 2), 256, 0, stream>>>(u_re, u_im, x, pt, qt);

    if (out_size == DIM * DIM) {
        hipMemsetAsync(d_out, 0, (size_t)DIM * DIM * sizeof(float), stream);
        gemm_stage2_atomic<<<dim3(16, 16, 2), 256, 0, stream>>>(u_re, u_im, pt, qt,
                                                                (float*)d_out);
    } else {
        gemm_stage2_cplx<<<dim3(16, 16), 256, 0, stream>>>(u_re, u_im, pt, qt,
                                                           (float2*)d_out,
                                                           (size_t)out_size / 2);
    }
}

// Round 12
// 268.992 us; speedup vs baseline: 1.5422x; 1.1457x over previous
//
#include <hip/hip_runtime.h>

typedef unsigned short u16;
typedef __attribute__((ext_vector_type(8))) short bf16x8;   // 8 bf16 in 4 VGPRs
typedef __attribute__((ext_vector_type(4))) float f32x4;
typedef __attribute__((ext_vector_type(4))) unsigned int u32x4;

#define DIM 2048

__device__ inline u16 f2bf(float f) {
    unsigned u = __builtin_bit_cast(unsigned, f);
    u = (u + 0x7FFFu + ((u >> 16) & 1u)) >> 16;   // RNE, finite inputs only
    return (u16)u;
}

__device__ inline void gl_lds16(const void* g, void* l) {
    __builtin_amdgcn_global_load_lds(
        (const __attribute__((address_space(1))) unsigned int*)g,
        (__attribute__((address_space(3))) unsigned int*)l, 16, 0, 0);
}

struct c32 { float x, y; };
__device__ inline c32 cmul(c32 a, c32 b) { return {a.x*b.x - a.y*b.y, a.x*b.y + a.y*b.x}; }

__device__ inline int slotf(int i) { return i + (i >> 5); }   // bank-pad layout

// ---------------------------------------------------------------------------
// Kernel 1: build T = U^T, one column per block, statevector in LDS.
// (p,p+6) qubit pairing + padded layout + single buffer. Validated round 8.
// ---------------------------------------------------------------------------
__global__ __launch_bounds__(256) void build_ut(const float* __restrict__ w,
                                                u16* __restrict__ ut_re,
                                                u16* __restrict__ ut_im) {
    __shared__ alignas(16) float gre[55][4], gim[55][4];
    __shared__ alignas(16) float G4r[5][5][16], G4i[5][5][16];
    __shared__ alignas(16) u16 ptab[DIM];
    __shared__ alignas(16) float vr[DIM + (DIM >> 5)], vi[DIM + (DIM >> 5)];
    const int tid = threadIdx.x;
    const int col = blockIdx.x;

    if (tid < 55) {
        const int layer = tid / 11, q = tid - layer * 11;
        const float WM = 0.63245553203367586f;   // sqrt(2)*5^-0.5
        float hx = 0.5f * WM * w[33*layer + q];
        float hy = 0.5f * WM * w[33*layer + 11 + q];
        float hz = 0.5f * WM * w[33*layer + 22 + q];
        float cx = cosf(hx), sx = sinf(hx);
        float cy = cosf(hy), sy = sinf(hy);
        float cz = cosf(hz), sz = sinf(hz);
        c32 m00{cy*cx,  sy*sx}, m01{-sy*cx, -cy*sx};
        c32 m10{sy*cx, -cy*sx}, m11{ cy*cx, -sy*sx};
        c32 em{cz, -sz}, ep{cz, sz};
        c32 r0 = cmul(em, m00), r1 = cmul(em, m01);
        c32 r2 = cmul(ep, m10), r3 = cmul(ep, m11);
        gre[tid][0] = r0.x; gim[tid][0] = r0.y;
        gre[tid][1] = r1.x; gim[tid][1] = r1.y;
        gre[tid][2] = r2.x; gim[tid][2] = r2.y;
        gre[tid][3] = r3.x; gim[tid][3] = r3.y;
    }
    for (int i = tid; i < DIM; i += 256) {
        vr[slotf(i)] = (i == col) ? 1.0f : 0.0f;
        vi[slotf(i)] = 0.0f;
        int jj = i;
        #pragma unroll
        for (int c = 10; c >= 0; --c) {
            int sc = 10 - c;
            int st = 10 - ((c + 1) % 11);
            jj ^= ((jj >> sc) & 1) << st;
        }
        ptab[i] = (u16)slotf(jj);
    }
    __syncthreads();

    for (int t = tid; t < 400; t += 256) {
        int layer = t / 80, r = t % 80, pair = r / 16, e = r % 16;
        int v = e >> 2, vp = e & 3;
        int a = v >> 1, b = v & 1, ap = vp >> 1, bp = vp & 1;
        int gia = layer * 11 + pair;        // qubit p  (bit 10-p)
        int gib = layer * 11 + 6 + pair;    // qubit p+6 (bit 4-p)
        c32 ga{gre[gia][a*2+ap], gim[gia][a*2+ap]};
        c32 gb{gre[gib][b*2+bp], gim[gib][b*2+bp]};
        c32 pr = cmul(ga, gb);
        G4r[layer][pair][e] = pr.x; G4i[layer][pair][e] = pr.y;
    }
    __syncthreads();

    for (int layer = 0; layer < 5; ++layer) {
        for (int p = 0; p < 5; ++p) {
            const int lo = 4 - p, hi = 10 - p;
            float g4r[16], g4i[16];
            #pragma unroll
            for (int e = 0; e < 16; ++e) {
                g4r[e] = G4r[layer][p][e];
                g4i[e] = G4i[layer][p][e];
            }
            const bool permRead = (layer > 0) && (p == 0);
            if (permRead) {
                float xr[2][4], xi[2][4];
                int es[2][4];
                #pragma unroll
                for (int h = 0; h < 2; ++h) {
                    int g = tid + h * 256;
                    int tmp = ((g >> lo) << (lo + 1)) | (g & ((1 << lo) - 1));
                    int i0  = ((tmp >> hi) << (hi + 1)) | (tmp & ((1 << hi) - 1));
                    #pragma unroll
                    for (int v = 0; v < 4; ++v) {
                        int e = i0 | ((v >> 1) << hi) | ((v & 1) << lo);
                        es[h][v] = slotf(e);
                        int ss = (int)ptab[e];
                        xr[h][v] = vr[ss]; xi[h][v] = vi[ss];
                    }
                }
                __syncthreads();
                #pragma unroll
                for (int h = 0; h < 2; ++h)
                    #pragma unroll
                    for (int v = 0; v < 4; ++v) {
                        float sr = 0.f, si = 0.f;
                        #pragma unroll
                        for (int u = 0; u < 4; ++u) {
                            sr += g4r[v*4+u] * xr[h][u] - g4i[v*4+u] * xi[h][u];
                            si += g4r[v*4+u] * xi[h][u] + g4i[v*4+u] * xr[h][u];
                        }
                        vr[es[h][v]] = sr; vi[es[h][v]] = si;
                    }
                __syncthreads();
            } else {
                #pragma unroll
                for (int h = 0; h < 2; ++h) {
                    int g = tid + h * 256;
                    int tmp = ((g >> lo) << (lo + 1)) | (g & ((1 << lo) - 1));
                    int i0  = ((tmp >> hi) << (hi + 1)) | (tmp & ((1 << hi) - 1));
                    float xr[4], xi[4];
                    int es[4];
                    #pragma unroll
                    for (int v = 0; v < 4; ++v) {
                        int e = i0 | ((v >> 1) << hi) | ((v & 1) << lo);
                        es[v] = slotf(e);
                        xr[v] = vr[es[v]]; xi[v] = vi[es[v]];
                    }
                    #pragma unroll
                    for (int v = 0; v < 4; ++v) {
                        float sr = 0.f, si = 0.f;
                        #pragma unroll
                        for (int u = 0; u < 4; ++u) {
                            sr += g4r[v*4+u] * xr[u] - g4i[v*4+u] * xi[u];
                            si += g4r[v*4+u] * xi[u] + g4i[v*4+u] * xr[u];
                        }
                        vr[es[v]] = sr; vi[es[v]] = si;
                    }
                }
                __syncthreads();
            }
        }
        {
            const int gi = layer * 11 + 5;
            const float g00r = gre[gi][0], g00i = gim[gi][0];
            const float g01r = gre[gi][1], g01i = gim[gi][1];
            const float g10r = gre[gi][2], g10i = gim[gi][2];
            const float g11r = gre[gi][3], g11i = gim[gi][3];
            #pragma unroll
            for (int t = 0; t < 4; ++t) {
                int p2 = tid + t * 256;
                int i0 = ((p2 >> 5) << 6) | (p2 & 31);
                int s0 = slotf(i0), s1 = slotf(i0 + 32);
                float ar = vr[s0], ai = vi[s0];
                float br = vr[s1], bi = vi[s1];
                vr[s0] = g00r*ar - g00i*ai + g01r*br - g01i*bi;
                vi[s0] = g00r*ai + g00i*ar + g01r*bi + g01i*br;
                vr[s1] = g10r*ar - g10i*ai + g11r*br - g11i*bi;
                vi[s1] = g10r*ai + g10i*ar + g11r*bi + g11i*br;
            }
            __syncthreads();
        }
    }
    for (int i = tid; i < DIM; i += 256) {
        ut_re[(size_t)col*DIM + i] = f2bf(vr[slotf(i)]);
        ut_im[(size_t)col*DIM + i] = f2bf(vi[slotf(i)]);
    }
}

// ---------------------------------------------------------------------------
// Kernel 2: bf16 transpose (U^T -> U), 64x64 LDS tiles; z selects re/im.
// ---------------------------------------------------------------------------
__global__ __launch_bounds__(256) void transpose2(const u16* __restrict__ sre,
                                                  const u16* __restrict__ sim,
                                                  u16* __restrict__ dre,
                                                  u16* __restrict__ dim_) {
    const u16* s = blockIdx.z ? sim : sre;
    u16*       d = blockIdx.z ? dim_ : dre;
    __shared__ alignas(16) u16 tile[64][66];
    const int bx = blockIdx.x * 64, by = blockIdx.y * 64;
    for (int e = threadIdx.x; e < 1024; e += 256) {
        int r = e >> 4, c4 = (e & 15) * 4;
        uint2 v = *(const uint2*)(s + (size_t)(by + r) * DIM + bx + c4);
        u16* tp = &tile[r][c4];
        tp[0] = (u16)(v.x); tp[1] = (u16)(v.x >> 16);
        tp[2] = (u16)(v.y); tp[3] = (u16)(v.y >> 16);
    }
    __syncthreads();
    for (int e = threadIdx.x; e < 1024; e += 256) {
        int r = e >> 4, c4 = (e & 15) * 4;
        unsigned lo = (unsigned)tile[c4][r]     | ((unsigned)tile[c4+1][r] << 16);
        unsigned hi = (unsigned)tile[c4+2][r]   | ((unsigned)tile[c4+3][r] << 16);
        *(uint2*)(d + (size_t)(bx + r) * DIM + by + c4) = make_uint2(lo, hi);
    }
}

// ---------------------------------------------------------------------------
// GEMM stage 1 (MFMA, PRODUCT-SPLIT, 128x128, BK=64 two-panel, double-buf):
//   z=0: pt[m,n] = sum_k Ure[m,k] X[n,k];  z=1: qt with Uim.
// BK=64 as two 32-col panels (each keeps the proven contiguous
// global_load_lds layout + 64B row stride). 32 K-iterations -> half the
// barrier/vmcnt(0) drains of BK=32. LDS 64 KB -> 2 blocks/CU.
// ---------------------------------------------------------------------------
__global__ __launch_bounds__(256, 2) void gemm_stage1(
        const u16* __restrict__ ure, const u16* __restrict__ uim,
        const float* __restrict__ x,
        u16* __restrict__ pt, u16* __restrict__ qt) {
    __shared__ alignas(16) u16 Ab[2][2][128*32], Bx[2][2][128*32]; // [buf][panel]
    const u16* A  = blockIdx.z ? uim : ure;
    u16*      dst = blockIdx.z ? qt  : pt;
    const int tid  = threadIdx.x;
    const int lane = tid & 63, w = tid >> 6;
    const int m0 = blockIdx.y * 128, n0 = blockIdx.x * 128;
    const int wm = (w >> 1) * 64, wn = (w & 1) * 64;
    const int ml = lane & 15, quad = lane >> 4;

    f32x4 acc[4][4];
    #pragma unroll
    for (int i = 0; i < 4; ++i)
        #pragma unroll
        for (int j = 0; j < 4; ++j) {
            f32x4 z = {0.f, 0.f, 0.f, 0.f};
            acc[i][j] = z;
        }

    auto stage = [&](int b, int k0) {   // stages both 32-col panels (64 cols)
        #pragma unroll
        for (int pn = 0; pn < 2; ++pn) {
            #pragma unroll
            for (int t = 0; t < 2; ++t) {
                int ci = t * 256 + tid;          // 16B chunk = 8 bf16
                int r = ci >> 2, c = ci & 3;
                size_t goA = ((size_t)(m0 + r) * DIM + k0 + pn * 32) * 2 + c * 16;
                gl_lds16((const char*)A + goA, (char*)Ab[b][pn] + ci * 16);
                const float4* src = (const float4*)(x + (size_t)(n0 + r) * DIM + k0 + pn * 32 + c * 8);
                float4 v0 = src[0], v1 = src[1];
                u32x4 pk;
                pk.x = (unsigned)f2bf(v0.x) | ((unsigned)f2bf(v0.y) << 16);
                pk.y = (unsigned)f2bf(v0.z) | ((unsigned)f2bf(v0.w) << 16);
                pk.z = (unsigned)f2bf(v1.x) | ((unsigned)f2bf(v1.y) << 16);
                pk.w = (unsigned)f2bf(v1.z) | ((unsigned)f2bf(v1.w) << 16);
                *(u32x4*)((char*)Bx[b][pn] + ci * 16) = pk;
            }
        }
    };

    stage(0, 0);
    __syncthreads();

    for (int k0 = 0; k0 < DIM; k0 += 64) {
        const int cb = (k0 >> 6) & 1;
        if (k0 + 64 < DIM) stage(cb ^ 1, k0 + 64);   // prefetch next 64-col tile

        #pragma unroll
        for (int pn = 0; pn < 2; ++pn) {
            bf16x8 af[4], bf[4];
            #pragma unroll
            for (int i = 0; i < 4; ++i) {
                af[i] = *(const bf16x8*)(Ab[cb][pn] + (wm + i*16 + ml) * 32 + quad * 8);
                bf[i] = *(const bf16x8*)(Bx[cb][pn] + (wn + i*16 + ml) * 32 + quad * 8);
            }
            #pragma unroll
            for (int i = 0; i < 4; ++i)
                #pragma unroll
                for (int j = 0; j < 4; ++j)
                    acc[i][j] = __builtin_amdgcn_mfma_f32_16x16x32_bf16(af[i], bf[j], acc[i][j], 0, 0, 0);
        }
        __syncthreads();
    }
    // C/D layout: col = lane&15, row = quad*4 + reg
    #pragma unroll
    for (int i = 0; i < 4; ++i)
        #pragma unroll
        for (int j = 0; j < 4; ++j) {
            int row = m0 + wm + i*16 + quad*4;
            int col = n0 + wn + j*16 + ml;
            #pragma unroll
            for (int r = 0; r < 4; ++r)
                dst[(size_t)(row + r) * DIM + col] = f2bf(acc[i][j][r]);
        }
}

// ---------------------------------------------------------------------------
// GEMM stage 2 (MFMA, PRODUCT-SPLIT, BK=64 two-panel, fp32 atomics):
//   z=0 adds Ure@pt^T tile, z=1 adds Uim@qt^T tile into memset d_out.
//   out[m,n] = Ure X Ure^T + Uim X Uim^T = Re(U X U^H).
// ---------------------------------------------------------------------------
__global__ __launch_bounds__(256, 2) void gemm_stage2_atomic(
        const u16* __restrict__ ure, const u16* __restrict__ uim,
        const u16* __restrict__ pt, const u16* __restrict__ qt,
        float* __restrict__ out) {
    __shared__ alignas(16) u16 Ab[2][2][128*32], Bb[2][2][128*32];
    const u16* A = blockIdx.z ? uim : ure;
    const u16* B = blockIdx.z ? qt  : pt;
    const int tid  = threadIdx.x;
    const int lane = tid & 63, w = tid >> 6;
    const int m0 = blockIdx.y * 128, n0 = blockIdx.x * 128;
    const int wm = (w >> 1) * 64, wn = (w & 1) * 64;
    const int ml = lane & 15, quad = lane >> 4;

    f32x4 acc[4][4];
    #pragma unroll
    for (int i = 0; i < 4; ++i)
        #pragma unroll
        for (int j = 0; j < 4; ++j) {
            f32x4 z = {0.f, 0.f, 0.f, 0.f};
            acc[i][j] = z;
        }

    auto stage = [&](int b, int k0) {
        #pragma unroll
        for (int pn = 0; pn < 2; ++pn) {
            #pragma unroll
            for (int t = 0; t < 2; ++t) {
                int ci = t * 256 + tid;
                int r = ci >> 2, c = ci & 3;
                size_t goA = ((size_t)(m0 + r) * DIM + k0 + pn * 32) * 2 + c * 16;
                size_t goB = ((size_t)(n0 + r) * DIM + k0 + pn * 32) * 2 + c * 16;
                gl_lds16((const char*)A + goA, (char*)Ab[b][pn] + ci * 16);
                gl_lds16((const char*)B + goB, (char*)Bb[b][pn] + ci * 16);
            }
        }
    };

    stage(0, 0);
    __syncthreads();

    for (int k0 = 0; k0 < DIM; k0 += 64) {
        const int cb = (k0 >> 6) & 1;
        if (k0 + 64 < DIM) stage(cb ^ 1, k0 + 64);   // prefetch next 64-col tile

        #pragma unroll
        for (int pn = 0; pn < 2; ++pn) {
            bf16x8 af[4], bf[4];
            #pragma unroll
            for (int i = 0; i < 4; ++i) {
                af[i] = *(const bf16x8*)(Ab[cb][pn] + (wm + i*16 + ml) * 32 + quad * 8);
                bf[i] = *(const bf16x8*)(Bb[cb][pn] + (wn + i*16 + ml) * 32 + quad * 8);
            }
            #pragma unroll
            for (int i = 0; i < 4; ++i)
                #pragma unroll
                for (int j = 0; j < 4; ++j)
                    acc[i][j] = __builtin_amdgcn_mfma_f32_16x16x32_bf16(af[i], bf[j], acc[i][j], 0, 0, 0);
        }
        __syncthreads();
    }
    #pragma unroll
    for (int i = 0; i < 4; ++i)
        #pragma unroll
        for (int j = 0; j < 4; ++j) {
            int row = m0 + wm + i*16 + quad*4;
            int col = n0 + wn + j*16 + ml;
            #pragma unroll
            for (int r = 0; r < 4; ++r)
                unsafeAtomicAdd(&out[(size_t)(row + r) * DIM + col], acc[i][j][r]);
        }
}

// ---------------------------------------------------------------------------
// Fallback (complex interleaved output) — insurance only, 128x128 1-buf LDS.
// ---------------------------------------------------------------------------
__global__ __launch_bounds__(256, 1) void gemm_stage2_cplx(
        const u16* __restrict__ ure, const u16* __restrict__ uim,
        const u16* __restrict__ pt, const u16* __restrict__ qt,
        float2* __restrict__ out, size_t out_lim) {
    __shared__ alignas(16) u16 Ar[128*32], Ai[128*32], Bp[128*32], Bq[128*32];
    const int tid  = threadIdx.x;
    const int lane = tid & 63, w = tid >> 6;
    const int m0 = blockIdx.y * 128, n0 = blockIdx.x * 128;
    const int wm = (w >> 1) * 64, wn = (w & 1) * 64;
    const int ml = lane & 15, quad = lane >> 4;

    f32x4 accR[4][4], accI[4][4];
    #pragma unroll
    for (int i = 0; i < 4; ++i)
        #pragma unroll
        for (int j = 0; j < 4; ++j) {
            f32x4 z = {0.f, 0.f, 0.f, 0.f};
            accR[i][j] = z; accI[i][j] = z;
        }

    for (int k0 = 0; k0 < DIM; k0 += 32) {
        #pragma unroll
        for (int t = 0; t < 2; ++t) {
            int ci = t * 256 + tid;
            int r = ci >> 2, c = ci & 3;
            size_t goA = ((size_t)(m0 + r) * DIM + k0) * 2 + c * 16;
            size_t goB = ((size_t)(n0 + r) * DIM + k0) * 2 + c * 16;
            gl_lds16((const char*)ure + goA, (char*)Ar + ci * 16);
            gl_lds16((const char*)uim + goA, (char*)Ai + ci * 16);
            gl_lds16((const char*)pt  + goB, (char*)Bp + ci * 16);
            gl_lds16((const char*)qt  + goB, (char*)Bq + ci * 16);
        }
        __syncthreads();
        bf16x8 ar[4], ai[4], bp[4], bq[4];
        #pragma unroll
        for (int i = 0; i < 4; ++i) {
            ar[i] = *(const bf16x8*)(Ar + (wm + i*16 + ml) * 32 + quad * 8);
            ai[i] = *(const bf16x8*)(Ai + (wm + i*16 + ml) * 32 + quad * 8);
            bp[i] = *(const bf16x8*)(Bp + (wn + i*16 + ml) * 32 + quad * 8);
            bq[i] = *(const bf16x8*)(Bq + (wn + i*16 + ml) * 32 + quad * 8);
        }
        #pragma unroll
        for (int i = 0; i < 4; ++i)
            #pragma unroll
            for (int j = 0; j < 4; ++j) {
                accR[i][j] = __builtin_amdgcn_mfma_f32_16x16x32_bf16(ar[i], bp[j], accR[i][j], 0, 0, 0);
                accR[i][j] = __builtin_amdgcn_mfma_f32_16x16x32_bf16(ai[i], bq[j], accR[i][j], 0, 0, 0);
                accI[i][j] = __builtin_amdgcn_mfma_f32_16x16x32_bf16(ai[i], bp[j], accI[i][j], 0, 0, 0);
                f32x4 t2 = __builtin_amdgcn_mfma_f32_16x16x32_bf16(ar[i], bq[j], {0.f,0.f,0.f,0.f}, 0, 0, 0);
                accI[i][j] -= t2;
            }
        __syncthreads();
    }
    #pragma unroll
    for (int i = 0; i < 4; ++i)
        #pragma unroll
        for (int j = 0; j < 4; ++j) {
            int row = m0 + wm + i*16 + quad*4;
            int col = n0 + wn + j*16 + ml;
            #pragma unroll
            for (int r = 0; r < 4; ++r) {
                size_t idx = (size_t)(row + r) * DIM + col;
                if (idx < out_lim)
                    out[idx] = make_float2(accR[i][j][r], accI[i][j][r]);
            }
        }
}

// ---------------------------------------------------------------------------
extern "C" void kernel_launch(void* const* d_in, const int* in_sizes, int n_in,
                              void* d_out, int out_size, void* d_ws, size_t ws_size,
                              hipStream_t stream) {
    int xi = (in_sizes[0] >= in_sizes[1]) ? 0 : 1;
    const float* x = (const float*)d_in[xi];
    const float* w = (const float*)d_in[1 - xi];

    char* ws = (char*)d_ws;
    const size_t P = (size_t)DIM * DIM * 2;   // one bf16 plane = 8 MiB
    if (ws_size < 4 * P) return;

    u16* ut_re = (u16*)(ws);
    u16* ut_im = (u16*)(ws + P);
    u16* u_re  = (u16*)(ws + 2*P);
    u16* u_im  = (u16*)(ws + 3*P);
    u16* pt    = ut_re;   // reuse after transpose
    u16* qt    = ut_im;

    build_ut<<<DIM, 256, 0, stream>>>(w, ut_re, ut_im);
    transpose2<<<dim3(32, 32, 2), 256, 0, stream>>>(ut_re, ut_im, u_re, u_im);
    gemm_stage1<<<dim3(16, 16, 2), 256, 0, stream>>>(u_re, u_im, x, pt, qt);

    if (out_size == DIM * DIM) {
        hipMemsetAsync(d_out, 0, (size_t)DIM * DIM * sizeof(float), stream);
        gemm_stage2_atomic<<<dim3(16, 16, 2), 256, 0, stream>>>(u_re, u_im, pt, qt,
                                                                (float*)d_out);
    } else {
        gemm_stage2_cplx<<<dim3(16, 16), 256, 0, stream>>>(u_re, u_im, pt, qt,
                                                           (float2*)d_out,
                                                           (size_t)out_size / 2);
    }
}

// Round 13
// 264.884 us; speedup vs baseline: 1.5661x; 1.0155x over previous
//
#include <hip/hip_runtime.h>

typedef unsigned short u16;
typedef __attribute__((ext_vector_type(8))) short bf16x8;   // 8 bf16 in 4 VGPRs
typedef __attribute__((ext_vector_type(4))) float f32x4;
typedef __attribute__((ext_vector_type(4))) unsigned int u32x4;

#define DIM 2048

__device__ inline u16 f2bf(float f) {
    unsigned u = __builtin_bit_cast(unsigned, f);
    u = (u + 0x7FFFu + ((u >> 16) & 1u)) >> 16;   // RNE, finite inputs only
    return (u16)u;
}

__device__ inline void gl_lds16(const void* g, void* l) {
    __builtin_amdgcn_global_load_lds(
        (const __attribute__((address_space(1))) unsigned int*)g,
        (__attribute__((address_space(3))) unsigned int*)l, 16, 0, 0);
}

struct c32 { float x, y; };
__device__ inline c32 cmul(c32 a, c32 b) { return {a.x*b.x - a.y*b.y, a.x*b.y + a.y*b.x}; }

__device__ inline int slot2(int i) { return i + (i >> 4); }   // float2 bank-pad

// complex butterfly: (u,w) <- (g0*u + g1*w, g2*u + g3*w)
__device__ inline void bfly(float2 g0, float2 g1, float2 g2, float2 g3,
                            float2& u, float2& w) {
    float2 nu, nw;
    nu.x = g0.x*u.x - g0.y*u.y + g1.x*w.x - g1.y*w.y;
    nu.y = g0.x*u.y + g0.y*u.x + g1.x*w.y + g1.y*w.x;
    nw.x = g2.x*u.x - g2.y*u.y + g3.x*w.x - g3.y*w.y;
    nw.y = g2.x*u.y + g2.y*u.x + g3.x*w.y + g3.y*w.x;
    u = nu; w = nw;
}

// ---------------------------------------------------------------------------
// Kernel 1: build T = U^T, one column per block, statevector in LDS (float2).
// Round-13 structure: per layer, 4 register-blocked rounds over bit-triples
// {10,9,8},{7,6,5},{4,3,2},{1,0}. Each thread loads its 8-element cube into
// registers, applies 3 (resp. 2) single-qubit gates sequentially (commuting,
// same FLOPs as fused pairs), writes back once. Ring perm (ptab, validated
// r6-r12) absorbed into round A of layers 1..4 via register staging.
// ---------------------------------------------------------------------------
__global__ __launch_bounds__(256) void build_ut(const float* __restrict__ w,
                                                u16* __restrict__ ut_re,
                                                u16* __restrict__ ut_im) {
    __shared__ alignas(16) float2 gg[55][4];          // 2x2 gates, row-major
    __shared__ alignas(16) u16 ptab[DIM];             // slot2(perm(e)), by e
    __shared__ alignas(16) float2 V[DIM + (DIM >> 4)];
    const int tid = threadIdx.x;
    const int col = blockIdx.x;

    if (tid < 55) {
        const int layer = tid / 11, q = tid - layer * 11;
        const float WM = 0.63245553203367586f;   // sqrt(2)*5^-0.5
        float hx = 0.5f * WM * w[33*layer + q];
        float hy = 0.5f * WM * w[33*layer + 11 + q];
        float hz = 0.5f * WM * w[33*layer + 22 + q];
        float cx = cosf(hx), sx = sinf(hx);
        float cy = cosf(hy), sy = sinf(hy);
        float cz = cosf(hz), sz = sinf(hz);
        c32 m00{cy*cx,  sy*sx}, m01{-sy*cx, -cy*sx};
        c32 m10{sy*cx, -cy*sx}, m11{ cy*cx, -sy*sx};
        c32 em{cz, -sz}, ep{cz, sz};
        c32 r0 = cmul(em, m00), r1 = cmul(em, m01);
        c32 r2 = cmul(ep, m10), r3 = cmul(ep, m11);
        gg[tid][0] = make_float2(r0.x, r0.y);
        gg[tid][1] = make_float2(r1.x, r1.y);
        gg[tid][2] = make_float2(r2.x, r2.y);
        gg[tid][3] = make_float2(r3.x, r3.y);
    }
    for (int i = tid; i < DIM; i += 256) {
        V[slot2(i)] = make_float2((i == col) ? 1.0f : 0.0f, 0.0f);
        int jj = i;
        #pragma unroll
        for (int c = 10; c >= 0; --c) {
            int sc = 10 - c;
            int st = 10 - ((c + 1) % 11);
            jj ^= ((jj >> sc) & 1) << st;
        }
        ptab[i] = (u16)slot2(jj);
    }
    __syncthreads();

    // 3-bit round: bits b2>b1>b0, gates gq2 on b2, gq1 on b1, gq0 on b0.
    auto round3 = [&](int b2, int b1, int b0, int gq2, int gq1, int gq0,
                      bool permRead) {
        int x = tid;
        x = ((x >> b0) << (b0 + 1)) | (x & ((1 << b0) - 1));
        x = ((x >> b1) << (b1 + 1)) | (x & ((1 << b1) - 1));
        x = ((x >> b2) << (b2 + 1)) | (x & ((1 << b2) - 1));
        float2 v[8]; int sl[8];
        #pragma unroll
        for (int j = 0; j < 8; ++j) {
            int e = x | ((j >> 2) << b2) | (((j >> 1) & 1) << b1) | ((j & 1) << b0);
            sl[j] = slot2(e);
            v[j] = V[permRead ? (int)ptab[e] : sl[j]];
        }
        if (permRead) __syncthreads();
        {   float2 g0 = gg[gq2][0], g1 = gg[gq2][1], g2 = gg[gq2][2], g3 = gg[gq2][3];
            bfly(g0,g1,g2,g3, v[0], v[4]); bfly(g0,g1,g2,g3, v[1], v[5]);
            bfly(g0,g1,g2,g3, v[2], v[6]); bfly(g0,g1,g2,g3, v[3], v[7]); }
        {   float2 g0 = gg[gq1][0], g1 = gg[gq1][1], g2 = gg[gq1][2], g3 = gg[gq1][3];
            bfly(g0,g1,g2,g3, v[0], v[2]); bfly(g0,g1,g2,g3, v[1], v[3]);
            bfly(g0,g1,g2,g3, v[4], v[6]); bfly(g0,g1,g2,g3, v[5], v[7]); }
        {   float2 g0 = gg[gq0][0], g1 = gg[gq0][1], g2 = gg[gq0][2], g3 = gg[gq0][3];
            bfly(g0,g1,g2,g3, v[0], v[1]); bfly(g0,g1,g2,g3, v[2], v[3]);
            bfly(g0,g1,g2,g3, v[4], v[5]); bfly(g0,g1,g2,g3, v[6], v[7]); }
        #pragma unroll
        for (int j = 0; j < 8; ++j) V[sl[j]] = v[j];
        __syncthreads();
    };

    // 2-bit round: bits {1,0}, gates gq1 on bit1, gq0 on bit0. In-place.
    auto round2 = [&](int gq1, int gq0) {
        float2 g10 = gg[gq1][0], g11 = gg[gq1][1], g12 = gg[gq1][2], g13 = gg[gq1][3];
        float2 g00 = gg[gq0][0], g01 = gg[gq0][1], g02 = gg[gq0][2], g03 = gg[gq0][3];
        #pragma unroll
        for (int h = 0; h < 2; ++h) {
            int i0 = (tid + h * 256) << 2;
            float2 v[4]; int sl[4];
            #pragma unroll
            for (int j = 0; j < 4; ++j) { sl[j] = slot2(i0 | j); v[j] = V[sl[j]]; }
            bfly(g10,g11,g12,g13, v[0], v[2]); bfly(g10,g11,g12,g13, v[1], v[3]);
            bfly(g00,g01,g02,g03, v[0], v[1]); bfly(g00,g01,g02,g03, v[2], v[3]);
            #pragma unroll
            for (int j = 0; j < 4; ++j) V[sl[j]] = v[j];
        }
        __syncthreads();
    };

    for (int layer = 0; layer < 5; ++layer) {
        const int gb = layer * 11;
        round3(10, 9, 8, gb + 0, gb + 1, gb + 2, layer > 0);  // qubits 0,1,2
        round3( 7, 6, 5, gb + 3, gb + 4, gb + 5, false);      // qubits 3,4,5
        round3( 4, 3, 2, gb + 6, gb + 7, gb + 8, false);      // qubits 6,7,8
        round2(gb + 9, gb + 10);                              // qubits 9,10
    }
    for (int i = tid; i < DIM; i += 256) {
        float2 v = V[slot2(i)];
        ut_re[(size_t)col*DIM + i] = f2bf(v.x);
        ut_im[(size_t)col*DIM + i] = f2bf(v.y);
    }
}

// ---------------------------------------------------------------------------
// Kernel 2: bf16 transpose (U^T -> U), 64x64 LDS tiles; z selects re/im.
// ---------------------------------------------------------------------------
__global__ __launch_bounds__(256) void transpose2(const u16* __restrict__ sre,
                                                  const u16* __restrict__ sim,
                                                  u16* __restrict__ dre,
                                                  u16* __restrict__ dim_) {
    const u16* s = blockIdx.z ? sim : sre;
    u16*       d = blockIdx.z ? dim_ : dre;
    __shared__ alignas(16) u16 tile[64][66];
    const int bx = blockIdx.x * 64, by = blockIdx.y * 64;
    for (int e = threadIdx.x; e < 1024; e += 256) {
        int r = e >> 4, c4 = (e & 15) * 4;
        uint2 v = *(const uint2*)(s + (size_t)(by + r) * DIM + bx + c4);
        u16* tp = &tile[r][c4];
        tp[0] = (u16)(v.x); tp[1] = (u16)(v.x >> 16);
        tp[2] = (u16)(v.y); tp[3] = (u16)(v.y >> 16);
    }
    __syncthreads();
    for (int e = threadIdx.x; e < 1024; e += 256) {
        int r = e >> 4, c4 = (e & 15) * 4;
        unsigned lo = (unsigned)tile[c4][r]     | ((unsigned)tile[c4+1][r] << 16);
        unsigned hi = (unsigned)tile[c4+2][r]   | ((unsigned)tile[c4+3][r] << 16);
        *(uint2*)(d + (size_t)(bx + r) * DIM + by + c4) = make_uint2(lo, hi);
    }
}

// ---------------------------------------------------------------------------
// GEMM stage 1 (MFMA, PRODUCT-SPLIT, 128x128, BK=64 two-panel, double-buf):
// Validated round 12. z=0: pt = Ure X^T; z=1: qt = Uim X^T.
// ---------------------------------------------------------------------------
__global__ __launch_bounds__(256, 2) void gemm_stage1(
        const u16* __restrict__ ure, const u16* __restrict__ uim,
        const float* __restrict__ x,
        u16* __restrict__ pt, u16* __restrict__ qt) {
    __shared__ alignas(16) u16 Ab[2][2][128*32], Bx[2][2][128*32]; // [buf][panel]
    const u16* A  = blockIdx.z ? uim : ure;
    u16*      dst = blockIdx.z ? qt  : pt;
    const int tid  = threadIdx.x;
    const int lane = tid & 63, w = tid >> 6;
    const int m0 = blockIdx.y * 128, n0 = blockIdx.x * 128;
    const int wm = (w >> 1) * 64, wn = (w & 1) * 64;
    const int ml = lane & 15, quad = lane >> 4;

    f32x4 acc[4][4];
    #pragma unroll
    for (int i = 0; i < 4; ++i)
        #pragma unroll
        for (int j = 0; j < 4; ++j) {
            f32x4 z = {0.f, 0.f, 0.f, 0.f};
            acc[i][j] = z;
        }

    auto stage = [&](int b, int k0) {   // stages both 32-col panels (64 cols)
        #pragma unroll
        for (int pn = 0; pn < 2; ++pn) {
            #pragma unroll
            for (int t = 0; t < 2; ++t) {
                int ci = t * 256 + tid;          // 16B chunk = 8 bf16
                int r = ci >> 2, c = ci & 3;
                size_t goA = ((size_t)(m0 + r) * DIM + k0 + pn * 32) * 2 + c * 16;
                gl_lds16((const char*)A + goA, (char*)Ab[b][pn] + ci * 16);
                const float4* src = (const float4*)(x + (size_t)(n0 + r) * DIM + k0 + pn * 32 + c * 8);
                float4 v0 = src[0], v1 = src[1];
                u32x4 pk;
                pk.x = (unsigned)f2bf(v0.x) | ((unsigned)f2bf(v0.y) << 16);
                pk.y = (unsigned)f2bf(v0.z) | ((unsigned)f2bf(v0.w) << 16);
                pk.z = (unsigned)f2bf(v1.x) | ((unsigned)f2bf(v1.y) << 16);
                pk.w = (unsigned)f2bf(v1.z) | ((unsigned)f2bf(v1.w) << 16);
                *(u32x4*)((char*)Bx[b][pn] + ci * 16) = pk;
            }
        }
    };

    stage(0, 0);
    __syncthreads();

    for (int k0 = 0; k0 < DIM; k0 += 64) {
        const int cb = (k0 >> 6) & 1;
        if (k0 + 64 < DIM) stage(cb ^ 1, k0 + 64);   // prefetch next 64-col tile

        #pragma unroll
        for (int pn = 0; pn < 2; ++pn) {
            bf16x8 af[4], bf[4];
            #pragma unroll
            for (int i = 0; i < 4; ++i) {
                af[i] = *(const bf16x8*)(Ab[cb][pn] + (wm + i*16 + ml) * 32 + quad * 8);
                bf[i] = *(const bf16x8*)(Bx[cb][pn] + (wn + i*16 + ml) * 32 + quad * 8);
            }
            #pragma unroll
            for (int i = 0; i < 4; ++i)
                #pragma unroll
                for (int j = 0; j < 4; ++j)
                    acc[i][j] = __builtin_amdgcn_mfma_f32_16x16x32_bf16(af[i], bf[j], acc[i][j], 0, 0, 0);
        }
        __syncthreads();
    }
    // C/D layout: col = lane&15, row = quad*4 + reg
    #pragma unroll
    for (int i = 0; i < 4; ++i)
        #pragma unroll
        for (int j = 0; j < 4; ++j) {
            int row = m0 + wm + i*16 + quad*4;
            int col = n0 + wn + j*16 + ml;
            #pragma unroll
            for (int r = 0; r < 4; ++r)
                dst[(size_t)(row + r) * DIM + col] = f2bf(acc[i][j][r]);
        }
}

// ---------------------------------------------------------------------------
// GEMM stage 2 (MFMA, PRODUCT-SPLIT, BK=64 two-panel, fp32 atomics):
// Validated round 12. out[m,n] = Ure X Ure^T + Uim X Uim^T = Re(U X U^H).
// ---------------------------------------------------------------------------
__global__ __launch_bounds__(256, 2) void gemm_stage2_atomic(
        const u16* __restrict__ ure, const u16* __restrict__ uim,
        const u16* __restrict__ pt, const u16* __restrict__ qt,
        float* __restrict__ out) {
    __shared__ alignas(16) u16 Ab[2][2][128*32], Bb[2][2][128*32];
    const u16* A = blockIdx.z ? uim : ure;
    const u16* B = blockIdx.z ? qt  : pt;
    const int tid  = threadIdx.x;
    const int lane = tid & 63, w = tid >> 6;
    const int m0 = blockIdx.y * 128, n0 = blockIdx.x * 128;
    const int wm = (w >> 1) * 64, wn = (w & 1) * 64;
    const int ml = lane & 15, quad = lane >> 4;

    f32x4 acc[4][4];
    #pragma unroll
    for (int i = 0; i < 4; ++i)
        #pragma unroll
        for (int j = 0; j < 4; ++j) {
            f32x4 z = {0.f, 0.f, 0.f, 0.f};
            acc[i][j] = z;
        }

    auto stage = [&](int b, int k0) {
        #pragma unroll
        for (int pn = 0; pn < 2; ++pn) {
            #pragma unroll
            for (int t = 0; t < 2; ++t) {
                int ci = t * 256 + tid;
                int r = ci >> 2, c = ci & 3;
                size_t goA = ((size_t)(m0 + r) * DIM + k0 + pn * 32) * 2 + c * 16;
                size_t goB = ((size_t)(n0 + r) * DIM + k0 + pn * 32) * 2 + c * 16;
                gl_lds16((const char*)A + goA, (char*)Ab[b][pn] + ci * 16);
                gl_lds16((const char*)B + goB, (char*)Bb[b][pn] + ci * 16);
            }
        }
    };

    stage(0, 0);
    __syncthreads();

    for (int k0 = 0; k0 < DIM; k0 += 64) {
        const int cb = (k0 >> 6) & 1;
        if (k0 + 64 < DIM) stage(cb ^ 1, k0 + 64);   // prefetch next 64-col tile

        #pragma unroll
        for (int pn = 0; pn < 2; ++pn) {
            bf16x8 af[4], bf[4];
            #pragma unroll
            for (int i = 0; i < 4; ++i) {
                af[i] = *(const bf16x8*)(Ab[cb][pn] + (wm + i*16 + ml) * 32 + quad * 8);
                bf[i] = *(const bf16x8*)(Bb[cb][pn] + (wn + i*16 + ml) * 32 + quad * 8);
            }
            #pragma unroll
            for (int i = 0; i < 4; ++i)
                #pragma unroll
                for (int j = 0; j < 4; ++j)
                    acc[i][j] = __builtin_amdgcn_mfma_f32_16x16x32_bf16(af[i], bf[j], acc[i][j], 0, 0, 0);
        }
        __syncthreads();
    }
    #pragma unroll
    for (int i = 0; i < 4; ++i)
        #pragma unroll
        for (int j = 0; j < 4; ++j) {
            int row = m0 + wm + i*16 + quad*4;
            int col = n0 + wn + j*16 + ml;
            #pragma unroll
            for (int r = 0; r < 4; ++r)
                unsafeAtomicAdd(&out[(size_t)(row + r) * DIM + col], acc[i][j][r]);
        }
}

// ---------------------------------------------------------------------------
// Fallback (complex interleaved output) — insurance only, 128x128 1-buf LDS.
// ---------------------------------------------------------------------------
__global__ __launch_bounds__(256, 1) void gemm_stage2_cplx(
        const u16* __restrict__ ure, const u16* __restrict__ uim,
        const u16* __restrict__ pt, const u16* __restrict__ qt,
        float2* __restrict__ out, size_t out_lim) {
    __shared__ alignas(16) u16 Ar[128*32], Ai[128*32], Bp[128*32], Bq[128*32];
    const int tid  = threadIdx.x;
    const int lane = tid & 63, w = tid >> 6;
    const int m0 = blockIdx.y * 128, n0 = blockIdx.x * 128;
    const int wm = (w >> 1) * 64, wn = (w & 1) * 64;
    const int ml = lane & 15, quad = lane >> 4;

    f32x4 accR[4][4], accI[4][4];
    #pragma unroll
    for (int i = 0; i < 4; ++i)
        #pragma unroll
        for (int j = 0; j < 4; ++j) {
            f32x4 z = {0.f, 0.f, 0.f, 0.f};
            accR[i][j] = z; accI[i][j] = z;
        }

    for (int k0 = 0; k0 < DIM; k0 += 32) {
        #pragma unroll
        for (int t = 0; t < 2; ++t) {
            int ci = t * 256 + tid;
            int r = ci >> 2, c = ci & 3;
            size_t goA = ((size_t)(m0 + r) * DIM + k0) * 2 + c * 16;
            size_t goB = ((size_t)(n0 + r) * DIM + k0) * 2 + c * 16;
            gl_lds16((const char*)ure + goA, (char*)Ar + ci * 16);
            gl_lds16((const char*)uim + goA, (char*)Ai + ci * 16);
            gl_lds16((const char*)pt  + goB, (char*)Bp + ci * 16);
            gl_lds16((const char*)qt  + goB, (char*)Bq + ci * 16);
        }
        __syncthreads();
        bf16x8 ar[4], ai[4], bp[4], bq[4];
        #pragma unroll
        for (int i = 0; i < 4; ++i) {
            ar[i] = *(const bf16x8*)(Ar + (wm + i*16 + ml) * 32 + quad * 8);
            ai[i] = *(const bf16x8*)(Ai + (wm + i*16 + ml) * 32 + quad * 8);
            bp[i] = *(const bf16x8*)(Bp + (wn + i*16 + ml) * 32 + quad * 8);
            bq[i] = *(const bf16x8*)(Bq + (wn + i*16 + ml) * 32 + quad * 8);
        }
        #pragma unroll
        for (int i = 0; i < 4; ++i)
            #pragma unroll
            for (int j = 0; j < 4; ++j) {
                accR[i][j] = __builtin_amdgcn_mfma_f32_16x16x32_bf16(ar[i], bp[j], accR[i][j], 0, 0, 0);
                accR[i][j] = __builtin_amdgcn_mfma_f32_16x16x32_bf16(ai[i], bq[j], accR[i][j], 0, 0, 0);
                accI[i][j] = __builtin_amdgcn_mfma_f32_16x16x32_bf16(ai[i], bp[j], accI[i][j], 0, 0, 0);
                f32x4 t2 = __builtin_amdgcn_mfma_f32_16x16x32_bf16(ar[i], bq[j], {0.f,0.f,0.f,0.f}, 0, 0, 0);
                accI[i][j] -= t2;
            }
        __syncthreads();
    }
    #pragma unroll
    for (int i = 0; i < 4; ++i)
        #pragma unroll
        for (int j = 0; j < 4; ++j) {
            int row = m0 + wm + i*16 + quad*4;
            int col = n0 + wn + j*16 + ml;
            #pragma unroll
            for (int r = 0; r < 4; ++r) {
                size_t idx = (size_t)(row + r) * DIM + col;
                if (idx < out_lim)
                    out[idx] = make_float2(accR[i][j][r], accI[i][j][r]);
            }
        }
}

// ---------------------------------------------------------------------------
extern "C" void kernel_launch(void* const* d_in, const int* in_sizes, int n_in,
                              void* d_out, int out_size, void* d_ws, size_t ws_size,
                              hipStream_t stream) {
    int xi = (in_sizes[0] >= in_sizes[1]) ? 0 : 1;
    const float* x = (const float*)d_in[xi];
    const float* w = (const float*)d_in[1 - xi];

    char* ws = (char*)d_ws;
    const size_t P = (size_t)DIM * DIM * 2;   // one bf16 plane = 8 MiB
    if (ws_size < 4 * P) return;

    u16* ut_re = (u16*)(ws);
    u16* ut_im = (u16*)(ws + P);
    u16* u_re  = (u16*)(ws + 2*P);
    u16* u_im  = (u16*)(ws + 3*P);
    u16* pt    = ut_re;   // reuse after transpose
    u16* qt    = ut_im;

    build_ut<<<DIM, 256, 0, stream>>>(w, ut_re, ut_im);
    transpose2<<<dim3(32, 32, 2), 256, 0, stream>>>(ut_re, ut_im, u_re, u_im);
    gemm_stage1<<<dim3(16, 16, 2), 256, 0, stream>>>(u_re, u_im, x, pt, qt);

    if (out_size == DIM * DIM) {
        hipMemsetAsync(d_out, 0, (size_t)DIM * DIM * sizeof(float), stream);
        gemm_stage2_atomic<<<dim3(16, 16, 2), 256, 0, stream>>>(u_re, u_im, pt, qt,
                                                                (float*)d_out);
    } else {
        gemm_stage2_cplx<<<dim3(16, 16), 256, 0, stream>>>(u_re, u_im, pt, qt,
                                                           (float2*)d_out,
                                                           (size_t)out_size / 2);
    }
}